// Round 2
// baseline (7648.589 us; speedup 1.0000x reference)
//
#include <hip/hip_runtime.h>
#include <math.h>

#define TPB 256

static __device__ __forceinline__ float4 mk4(float a, float b, float c, float d) {
  float4 r; r.x = a; r.y = b; r.z = c; r.w = d; return r;
}

// ---------------------------------------------------------------------------
// RoPE cos/sin tables, replicating JAX f32 arithmetic exactly. (unchanged)
// ---------------------------------------------------------------------------
__global__ __launch_bounds__(TPB) void k_tables(float* __restrict__ cosb,
                                                float* __restrict__ sinb) {
  int gid = blockIdx.x * TPB + threadIdx.x;
  if (gid >= 1024 * 32) return;
  int t = gid >> 5, j = gid & 31;
  const double Ld = 1.3222192947339193;  // python math.log10(21.0)
  float Lf = (float)Ld;
  float mlog;
  if (j == 31) {
    mlog = Lf;
  } else {
    float stepf = (float)((double)j / 31.0);
    mlog = (float)((double)Lf * (double)stepf);
  }
  float p = (float)pow(10.0, (double)mlog);
  float mel = p - 1.0f;
  float t2 = (200.0f * mel) / 1000.0f;
  float freq = 163.63636363636363f * t2;
  float ang = (float)t * freq;
  double a = (double)ang;
  cosb[gid] = (float)cos(a);
  sinb[gid] = (float)sin(a);
}

// ---------------------------------------------------------------------------
// Per-row 1/rms over D=1024 (unchanged)
// ---------------------------------------------------------------------------
__global__ __launch_bounds__(TPB) void k_rowinv(const float* __restrict__ X,
                                                float* __restrict__ inv) {
  __shared__ float red[4];
  int row = blockIdx.x;
  int tid = threadIdx.x;
  float4 v = *(const float4*)(X + (size_t)row * 1024 + tid * 4);
  float ss = v.x * v.x + v.y * v.y + v.z * v.z + v.w * v.w;
#pragma unroll
  for (int m = 1; m < 64; m <<= 1) ss += __shfl_xor(ss, m);
  if ((tid & 63) == 0) red[tid >> 6] = ss;
  __syncthreads();
  if (tid == 0) {
    float s = ((red[0] + red[1]) + (red[2] + red[3]));
    float mm = s * (1.0f / 1024.0f) + 1.1920928955078125e-7f;
    inv[row] = (float)(1.0 / sqrt((double)mm));
  }
}

// ---------------------------------------------------------------------------
// Tiled f32 GEMM, 128x128 block, BK=16, 8x8 per thread (split 4+4 frags).
// C = (X * inv[row] * wn[k]) @ W + bias.  M=4096, K=1024.
// mode 0: row-major [4096][N] into o0
// mode 1: N=1024, scatter to o0[((b*16+ch)*1024+t)*64+d]
// mode 2: N=2048, cols<1024 -> o0 (K), cols>=1024 -> o1 (V)
// k-order sequential 0..1023 per output (numerics == previous version).
// ---------------------------------------------------------------------------
__global__ __launch_bounds__(TPB, 4) void k_gemm128(
    const float* __restrict__ X, const float* __restrict__ inv,
    const float* __restrict__ wn, const float* __restrict__ W,
    const float* __restrict__ bias, float* __restrict__ o0,
    float* __restrict__ o1, int N, int mode) {
  __shared__ float As[16][132];
  __shared__ float Bs[16][132];
  int tid = threadIdx.x;
  int bx = blockIdx.x, by = blockIdx.y;
  int tx = tid & 15, ty = tid >> 4;
  float c[8][8];
#pragma unroll
  for (int i = 0; i < 8; ++i)
#pragma unroll
    for (int j = 0; j < 8; ++j) c[i][j] = 0.0f;

  int arow = tid >> 1;               // 0..127
  float sA = 1.0f;
  if (inv) sA = inv[by * 128 + arow];
  const float* Xrow = X + (size_t)(by * 128 + arow) * 1024;

  for (int k0 = 0; k0 < 1024; k0 += 16) {
    // stage A (transposed, scaled): 2 float4 per thread
#pragma unroll
    for (int u = 0; u < 2; ++u) {
      int kq = ((tid & 1) * 2 + u) * 4;
      float4 a4 = *(const float4*)(Xrow + k0 + kq);
      if (wn) {
        float4 w4 = *(const float4*)(wn + k0 + kq);
        a4.x *= w4.x; a4.y *= w4.y; a4.z *= w4.z; a4.w *= w4.w;
      }
      a4.x *= sA; a4.y *= sA; a4.z *= sA; a4.w *= sA;
      As[kq + 0][arow] = a4.x;
      As[kq + 1][arow] = a4.y;
      As[kq + 2][arow] = a4.z;
      As[kq + 3][arow] = a4.w;
    }
    // stage B: 2 float4 per thread
#pragma unroll
    for (int u = 0; u < 2; ++u) {
      int kr = tid >> 4;
      int c4 = ((tid & 15) * 2 + u) * 4;
      *(float4*)&Bs[kr][c4] =
          *(const float4*)(W + (size_t)(k0 + kr) * N + bx * 128 + c4);
    }
    __syncthreads();
#pragma unroll
    for (int kk = 0; kk < 16; ++kk) {
      float4 a0 = *(const float4*)&As[kk][ty * 4];
      float4 a1 = *(const float4*)&As[kk][64 + ty * 4];
      float4 b0 = *(const float4*)&Bs[kk][tx * 4];
      float4 b1 = *(const float4*)&Bs[kk][64 + tx * 4];
      float av[8] = {a0.x, a0.y, a0.z, a0.w, a1.x, a1.y, a1.z, a1.w};
      float bv[8] = {b0.x, b0.y, b0.z, b0.w, b1.x, b1.y, b1.z, b1.w};
#pragma unroll
      for (int i = 0; i < 8; ++i)
#pragma unroll
        for (int j = 0; j < 8; ++j) c[i][j] += av[i] * bv[j];
    }
    __syncthreads();
  }

  // writeback
#pragma unroll
  for (int jh = 0; jh < 2; ++jh) {
    int colbase = bx * 128 + jh * 64 + tx * 4;
    float4 bb = {0.f, 0.f, 0.f, 0.f};
    if (bias) bb = *(const float4*)(bias + colbase);
#pragma unroll
    for (int ih = 0; ih < 2; ++ih) {
#pragma unroll
      for (int i2 = 0; i2 < 4; ++i2) {
        int row = by * 128 + ih * 64 + ty * 4 + i2;
        int ci = ih * 4 + i2;
        float4 o;
        o.x = c[ci][jh * 4 + 0] + bb.x;
        o.y = c[ci][jh * 4 + 1] + bb.y;
        o.z = c[ci][jh * 4 + 2] + bb.z;
        o.w = c[ci][jh * 4 + 3] + bb.w;
        if (mode == 0) {
          *(float4*)(o0 + (size_t)row * N + colbase) = o;
        } else {
          int b = row >> 10, t = row & 1023;
          float* dst = o0;
          int cc = colbase;
          if (mode == 2 && colbase >= 1024) { dst = o1; cc = colbase - 1024; }
          int ch = cc >> 6, d = cc & 63;
          *(float4*)(dst + ((size_t)((b * 16 + ch) * 1024 + t)) * 64 + d) = o;
        }
      }
    }
  }
}

// ---------------------------------------------------------------------------
// In-place RoPE (unchanged)
// ---------------------------------------------------------------------------
__global__ __launch_bounds__(TPB) void k_rope(float* __restrict__ A, int mask,
                                              const float* __restrict__ cosb,
                                              const float* __restrict__ sinb) {
  int gid = blockIdx.x * TPB + threadIdx.x;
  int j = gid & 31;
  int row = gid >> 5;
  int t = row & 1023;
  int aidx = ((t & mask) << 5) + j;
  float cc = cosb[aidx], sn = sinb[aidx];
  size_t base = (size_t)row * 64;
  float x1 = A[base + 2 * j], x2 = A[base + 2 * j + 1];
  A[base + 2 * j] = x1 * cc - x2 * sn;
  A[base + 2 * j + 1] = x1 * sn + x2 * cc;
}

// ---------------------------------------------------------------------------
// Slide gather (unchanged)
// ---------------------------------------------------------------------------
__global__ __launch_bounds__(TPB) void k_gather(
    const float* __restrict__ K, const float* __restrict__ V,
    float* __restrict__ kc, float* __restrict__ vc,
    const float* __restrict__ cosb, const float* __restrict__ sinb) {
  int gid = blockIdx.x * TPB + threadIdx.x;
  int j = gid & 31;
  int tl = (gid >> 5) & 63;
  int win = (gid >> 11) & 15;
  int h = (gid >> 15) & 15;
  int b = gid >> 19;
  int sw = win * 64 - 4;
  if (win == 0) sw = 0;
  size_t bh = (size_t)(b * 16 + h) * 1024;
  size_t src = (bh + sw + tl) * 64;
  size_t dst = (bh + win * 64 + tl) * 64;
  int aidx = (tl << 5) + j;
  float cc = cosb[aidx], sn = sinb[aidx];
  float k1 = K[src + 2 * j], k2 = K[src + 2 * j + 1];
  kc[dst + 2 * j] = k1 * cc - k2 * sn;
  kc[dst + 2 * j + 1] = k1 * sn + k2 * cc;
  vc[dst + 2 * j] = V[src + 2 * j];
  vc[dst + 2 * j + 1] = V[src + 2 * j + 1];
}

// ---------------------------------------------------------------------------
// Projections: qp (rms-normed) -> qph row-major; kp raw -> kc, normed ->
// kphT TRANSPOSED [(bh*64+d)*1024 + t]; vp -> vc.  W mats staged in LDS.
// ---------------------------------------------------------------------------
__global__ __launch_bounds__(TPB) void k_proj(
    const float* __restrict__ curq, float* __restrict__ kc,
    float* __restrict__ vc, float* __restrict__ qph, float* __restrict__ kphT,
    const float* __restrict__ Wlq, const float* __restrict__ blq,
    const float* __restrict__ Wlk, const float* __restrict__ blk,
    const float* __restrict__ Wlv, const float* __restrict__ blv,
    const float* __restrict__ wln, int CQ, const int* __restrict__ flags) {
  int RT = CQ >> 4;
  int bid = blockIdx.x;
  int rt = bid % RT;
  int rest = bid / RT;
  int h = rest & 15; rest >>= 4;
  int b = rest & 3;
  int win = rest >> 2;
  if (flags && flags[win]) return;
  __shared__ float qs[16][68], ksm[16][68], vsm[16][68];
  __shared__ float Wqs[4096], Wks[4096], Wvs[4096];
  int tid = threadIdx.x;
  // stage weights
#pragma unroll
  for (int i = 0; i < 4; ++i) {
    int f4 = (i * 256 + tid) * 4;
    *(float4*)&Wqs[f4] = *(const float4*)(Wlq + f4);
    *(float4*)&Wks[f4] = *(const float4*)(Wlk + f4);
    *(float4*)&Wvs[f4] = *(const float4*)(Wlv + f4);
  }
  int lr = tid >> 4, c4 = (tid & 15) * 4;
  int bh = b * 16 + h;
  size_t rowbase = (size_t)bh * 1024 + (size_t)win * CQ + rt * 16;
  size_t g = (rowbase + lr) * 64 + c4;
  *(float4*)&qs[lr][c4] = *(const float4*)(curq + g);
  *(float4*)&ksm[lr][c4] = *(const float4*)(kc + g);
  *(float4*)&vsm[lr][c4] = *(const float4*)(vc + g);
  __syncthreads();
  int r = tid >> 4, cg = tid & 15;
  int tglob = win * CQ + rt * 16 + r;
  const float eps = 1.1920928955078125e-7f;
  float4 wl4 = *(const float4*)(wln + cg * 4);
  size_t orow = (rowbase + r) * 64 + cg * 4;
  float4 acc;
  float ssum, rms;
  // ---- Q
  acc = *(const float4*)(blq + cg * 4);
#pragma unroll 8
  for (int k = 0; k < 64; ++k) {
    float xv = qs[r][k];
    float4 w4 = *(const float4*)&Wqs[k * 64 + cg * 4];
    acc.x += xv * w4.x; acc.y += xv * w4.y;
    acc.z += xv * w4.z; acc.w += xv * w4.w;
  }
  ssum = acc.x * acc.x + acc.y * acc.y + acc.z * acc.z + acc.w * acc.w;
#pragma unroll
  for (int m = 1; m < 16; m <<= 1) ssum += __shfl_xor(ssum, m);
  rms = (float)(1.0 / sqrt((double)(ssum * 0.015625f + eps)));
  {
    float4 o;
    o.x = acc.x * rms * wl4.x; o.y = acc.y * rms * wl4.y;
    o.z = acc.z * rms * wl4.z; o.w = acc.w * rms * wl4.w;
    *(float4*)(qph + orow) = o;
  }
  // ---- K
  acc = *(const float4*)(blk + cg * 4);
#pragma unroll 8
  for (int k = 0; k < 64; ++k) {
    float xv = ksm[r][k];
    float4 w4 = *(const float4*)&Wks[k * 64 + cg * 4];
    acc.x += xv * w4.x; acc.y += xv * w4.y;
    acc.z += xv * w4.z; acc.w += xv * w4.w;
  }
  *(float4*)(kc + orow) = acc;  // raw kp -> next kc
  ssum = acc.x * acc.x + acc.y * acc.y + acc.z * acc.z + acc.w * acc.w;
#pragma unroll
  for (int m = 1; m < 16; m <<= 1) ssum += __shfl_xor(ssum, m);
  rms = (float)(1.0 / sqrt((double)(ssum * 0.015625f + eps)));
  {
    float no0 = acc.x * rms * wl4.x;
    float no1 = acc.y * rms * wl4.y;
    float no2 = acc.z * rms * wl4.z;
    float no3 = acc.w * rms * wl4.w;
    size_t tb = (size_t)bh * 64 + cg * 4;
    kphT[(tb + 0) * 1024 + tglob] = no0;
    kphT[(tb + 1) * 1024 + tglob] = no1;
    kphT[(tb + 2) * 1024 + tglob] = no2;
    kphT[(tb + 3) * 1024 + tglob] = no3;
  }
  // ---- V
  acc = *(const float4*)(blv + cg * 4);
#pragma unroll 8
  for (int k = 0; k < 64; ++k) {
    float xv = vsm[r][k];
    float4 w4 = *(const float4*)&Wvs[k * 64 + cg * 4];
    acc.x += xv * w4.x; acc.y += xv * w4.y;
    acc.z += xv * w4.z; acc.w += xv * w4.w;
  }
  *(float4*)(vc + orow) = acc;
}

// ---------------------------------------------------------------------------
// Attention, outer-product register-blocked flash.  QTILE = FRAG*16 q-rows
// per block, key tiles of 64.  Q transposed once into LDS; K read from
// kphT (pre-transposed); P staged into the K buffer for the PV stage.
// mode 0 (it0): prev=attn, curq+=attn
// mode 1 (it1): curq+=attn, out=attn, diffp[bid]=sum|attn-prev|
// mode 2 (it2): skip if flags, else out=attn
// ---------------------------------------------------------------------------
template <int FRAG>
__global__ __launch_bounds__(TPB, 2) void k_attn_t(
    const float* __restrict__ qph, const float* __restrict__ kphT,
    const float* __restrict__ vbuf, float* __restrict__ curq,
    float* __restrict__ prevb, float* __restrict__ outb,
    float* __restrict__ diffp, const int* __restrict__ flags, int NQT,
    int nt, int mode) {
  constexpr int QT = FRAG * 16;
  int bid = blockIdx.x;
  int qt = bid % NQT;
  int bh = bid / NQT;
  int h = bh & 15, b = bh >> 4;
  if (mode == 2 && flags[(nt == 1) ? qt : 0]) return;
  __shared__ float qTs[64][QT];
  __shared__ float kps[64 * QT];  // kT [d][k<64] then pT [k][q]
  __shared__ float vss[64 * 64];
  int tid = threadIdx.x;
  int tx = tid & 15, ty = tid >> 4;
  size_t bh1024 = (size_t)bh * 1024;
  size_t bh64 = (size_t)bh * 64;
  int q0 = qt * QT;
  // transpose Q into LDS
#pragma unroll
  for (int i = 0; i < FRAG; ++i) {
    int f4id = i * 256 + tid;
    int row = f4id >> 4;
    int c4 = (f4id & 15) * 4;
    float4 v = *(const float4*)(qph + (bh1024 + q0 + row) * 64 + c4);
    qTs[c4 + 0][row] = v.x;
    qTs[c4 + 1][row] = v.y;
    qTs[c4 + 2][row] = v.z;
    qTs[c4 + 3][row] = v.w;
  }
  float m[FRAG], l[FRAG], acc[FRAG][4];
#pragma unroll
  for (int i = 0; i < FRAG; ++i) {
    m[i] = -INFINITY; l[i] = 0.0f;
    acc[i][0] = acc[i][1] = acc[i][2] = acc[i][3] = 0.0f;
  }
  int kstart = (nt == 1) ? q0 : 0;
  const float SCL = 0.18033688011112042f;  // log2(e)/8

  for (int kt = 0; kt < nt; ++kt) {
    int k0 = kstart + kt * 64;
    // stage K tile (transposed layout from kphT) and V tile
#pragma unroll
    for (int i = 0; i < 4; ++i) {
      int f4id = i * 256 + tid;
      int rr = f4id >> 4;
      int c4 = (f4id & 15) * 4;
      *(float4*)&kps[rr * QT + c4] =
          *(const float4*)(kphT + (bh64 + rr) * 1024 + k0 + c4);
      *(float4*)&vss[rr * 64 + c4] =
          *(const float4*)(vbuf + (bh1024 + k0 + rr) * 64 + c4);
    }
    __syncthreads();
    // S = qT^T * kT  (outer product over d)
    float s[FRAG][4];
#pragma unroll
    for (int i = 0; i < FRAG; ++i)
      s[i][0] = s[i][1] = s[i][2] = s[i][3] = 0.0f;
#pragma unroll 4
    for (int d = 0; d < 64; ++d) {
      float4 kv = *(const float4*)&kps[d * QT + tx * 4];
      float4 qa0 = *(const float4*)&qTs[d][ty * FRAG];
      float qv[FRAG];
      qv[0] = qa0.x; qv[1] = qa0.y; qv[2] = qa0.z; qv[3] = qa0.w;
      if (FRAG == 8) {
        float4 qa1 = *(const float4*)&qTs[d][ty * FRAG + 4];
        qv[4] = qa1.x; qv[5] = qa1.y; qv[6] = qa1.z; qv[7] = qa1.w;
      }
#pragma unroll
      for (int i = 0; i < FRAG; ++i) {
        s[i][0] += qv[i] * kv.x;
        s[i][1] += qv[i] * kv.y;
        s[i][2] += qv[i] * kv.z;
        s[i][3] += qv[i] * kv.w;
      }
    }
    // online softmax (log2 domain)
#pragma unroll
    for (int i = 0; i < FRAG; ++i) {
      s[i][0] *= SCL; s[i][1] *= SCL; s[i][2] *= SCL; s[i][3] *= SCL;
      float r0 = fmaxf(fmaxf(s[i][0], s[i][1]), fmaxf(s[i][2], s[i][3]));
#pragma unroll
      for (int mm = 1; mm < 16; mm <<= 1) r0 = fmaxf(r0, __shfl_xor(r0, mm));
      float mnew = fmaxf(m[i], r0);
      float sc = exp2f(m[i] - mnew);
      float rs = 0.0f;
#pragma unroll
      for (int j = 0; j < 4; ++j) {
        float pv = exp2f(s[i][j] - mnew);
        s[i][j] = pv;
        rs += pv;
      }
#pragma unroll
      for (int mm = 1; mm < 16; mm <<= 1) rs += __shfl_xor(rs, mm);
      l[i] = l[i] * sc + rs;
      m[i] = mnew;
      acc[i][0] *= sc; acc[i][1] *= sc; acc[i][2] *= sc; acc[i][3] *= sc;
    }
    __syncthreads();  // all S reads of kps done
    // write P transposed: pT[k][q]
#pragma unroll
    for (int jj = 0; jj < 4; ++jj) {
      *(float4*)&kps[(tx * 4 + jj) * QT + ty * FRAG] =
          mk4(s[0][jj], s[1][jj], s[2][jj], s[3][jj]);
      if (FRAG == 8)
        *(float4*)&kps[(tx * 4 + jj) * QT + ty * FRAG + 4] =
            mk4(s[4][jj], s[5][jj], s[6][jj], s[7][jj]);
    }
    __syncthreads();
    // PV: acc += pT^T * V (outer product over k)
#pragma unroll 4
    for (int k = 0; k < 64; ++k) {
      float4 vv = *(const float4*)&vss[k * 64 + tx * 4];
      float4 pa0 = *(const float4*)&kps[k * QT + ty * FRAG];
      float pv[FRAG];
      pv[0] = pa0.x; pv[1] = pa0.y; pv[2] = pa0.z; pv[3] = pa0.w;
      if (FRAG == 8) {
        float4 pa1 = *(const float4*)&kps[k * QT + ty * FRAG + 4];
        pv[4] = pa1.x; pv[5] = pa1.y; pv[6] = pa1.z; pv[7] = pa1.w;
      }
#pragma unroll
      for (int i = 0; i < FRAG; ++i) {
        acc[i][0] += pv[i] * vv.x;
        acc[i][1] += pv[i] * vv.y;
        acc[i][2] += pv[i] * vv.z;
        acc[i][3] += pv[i] * vv.w;
      }
    }
    __syncthreads();
  }
  // epilogue
  float ds = 0.0f;
#pragma unroll
  for (int i = 0; i < FRAG; ++i) {
    int t = q0 + ty * FRAG + i;
    float4 att;
    att.x = acc[i][0] / l[i];
    att.y = acc[i][1] / l[i];
    att.z = acc[i][2] / l[i];
    att.w = acc[i][3] / l[i];
    size_t base = (bh1024 + t) * 64 + tx * 4;
    size_t obase = ((size_t)b * 1024 + t) * 1024 + h * 64 + tx * 4;
    if (mode == 0) {
      *(float4*)(prevb + base) = att;
      float4 cq = *(const float4*)(curq + base);
      cq.x += att.x; cq.y += att.y; cq.z += att.z; cq.w += att.w;
      *(float4*)(curq + base) = cq;
    } else if (mode == 1) {
      float4 pv = *(const float4*)(prevb + base);
      ds += fabsf(att.x - pv.x) + fabsf(att.y - pv.y) +
            fabsf(att.z - pv.z) + fabsf(att.w - pv.w);
      float4 cq = *(const float4*)(curq + base);
      cq.x += att.x; cq.y += att.y; cq.z += att.z; cq.w += att.w;
      *(float4*)(curq + base) = cq;
      *(float4*)(outb + obase) = att;
    } else {
      *(float4*)(outb + obase) = att;
    }
  }
  if (mode == 1) {
    float* red = vss;  // vss dead
    red[tid] = ds;
    __syncthreads();
    for (int s2 = 128; s2 > 0; s2 >>= 1) {
      if (tid < s2) red[tid] += red[tid + s2];
      __syncthreads();
    }
    if (tid == 0) diffp[bid] = red[0];
  }
}

// Deterministic diff finalize.  flags[w] = mean over window < 0.5
__global__ __launch_bounds__(64) void k_finalize(const float* __restrict__ diffp,
                                                 int* __restrict__ flags,
                                                 int nwin, int nper,
                                                 float count) {
  int w = threadIdx.x;
  if (w < nwin) {
    float s = 0.0f;
    for (int i = 0; i < nper; ++i) s += diffp[w + i * nwin];
    flags[w] = (s / count < 0.5f) ? 1 : 0;
  }
}

// ---------------------------------------------------------------------------
extern "C" void kernel_launch(void* const* d_in, const int* in_sizes, int n_in,
                              void* d_out, int out_size, void* d_ws,
                              size_t ws_size, hipStream_t stream) {
  const float* x = (const float*)d_in[0];
  const float* xa = (const float*)d_in[1];
  const float* wqn = (const float*)d_in[2];
  const float* Wq = (const float*)d_in[3];
  const float* bq = (const float*)d_in[4];
  const float* wkvn = (const float*)d_in[5];
  const float* Wkv = (const float*)d_in[6];
  const float* bkv = (const float*)d_in[7];
  const float* wln = (const float*)d_in[8];
  const float* Wlq = (const float*)d_in[9];
  const float* blq = (const float*)d_in[10];
  const float* Wlk = (const float*)d_in[11];
  const float* blk = (const float*)d_in[12];
  const float* Wlv = (const float*)d_in[13];
  const float* blv = (const float*)d_in[14];
  const float* Wo = (const float*)d_in[15];
  const float* bo = (const float*)d_in[16];

  float* ws = (float*)d_ws;
  const size_t SLOT = (size_t)4 * 16 * 1024 * 64;  // 16 MiB
  float* xw = ws;
  float* xaw = ws + SLOT;
  float* Q = ws + 2 * SLOT;  // curq
  float* K = ws + 3 * SLOT;
  float* V = ws + 4 * SLOT;
  float* kc = ws + 5 * SLOT;
  float* vc = ws + 6 * SLOT;
  float* prev = ws + 7 * SLOT;
  float* qph = ws + 8 * SLOT;
  float* kphT = ws + 9 * SLOT;
  float* misc = ws + 10 * SLOT;
  float* inv = misc;
  float* cosb = misc + 8192;
  float* sinb = cosb + 32768;
  float* diffp = sinb + 32768;
  int* flags = (int*)(diffp + 4096);

  k_tables<<<128, TPB, 0, stream>>>(cosb, sinb);

  for (int sl = 0; sl < 2; ++sl) {
    const float* Xin = sl ? xa : x;
    float* Xout = sl ? xaw : xw;
    k_rowinv<<<4096, TPB, 0, stream>>>(Xin, inv);
    k_gemm128<<<dim3(8, 32), TPB, 0, stream>>>(Xin, inv, wqn, Wq, bq, Q, nullptr, 1024, 1);
    k_gemm128<<<dim3(16, 32), TPB, 0, stream>>>(Xin, inv, wkvn, Wkv, bkv, K, V, 2048, 2);
    k_rope<<<8192, TPB, 0, stream>>>(Q, 63, cosb, sinb);
    k_gather<<<8192, TPB, 0, stream>>>(K, V, kc, vc, cosb, sinb);
    // it0
    k_proj<<<4096, TPB, 0, stream>>>(Q, kc, vc, qph, kphT, Wlq, blq, Wlk, blk, Wlv, blv, wln, 64, nullptr);
    k_attn_t<4><<<1024, TPB, 0, stream>>>(qph, kphT, vc, Q, prev, Xout, diffp, nullptr, 16, 1, 0);
    // it1
    k_proj<<<4096, TPB, 0, stream>>>(Q, kc, vc, qph, kphT, Wlq, blq, Wlk, blk, Wlv, blv, wln, 64, nullptr);
    k_attn_t<4><<<1024, TPB, 0, stream>>>(qph, kphT, vc, Q, prev, Xout, diffp, nullptr, 16, 1, 1);
    k_finalize<<<1, 64, 0, stream>>>(diffp, flags, 16, 64, 262144.0f);
    // it2
    k_proj<<<4096, TPB, 0, stream>>>(Q, kc, vc, qph, kphT, Wlq, blq, Wlk, blk, Wlv, blv, wln, 64, flags);
    k_attn_t<4><<<1024, TPB, 0, stream>>>(qph, kphT, vc, Q, prev, Xout, diffp, flags, 16, 1, 2);
  }

  // final focus: cq = ck = 1024
  k_rowinv<<<4096, TPB, 0, stream>>>(xw, inv);
  k_gemm128<<<dim3(8, 32), TPB, 0, stream>>>(xw, inv, wqn, Wq, bq, Q, nullptr, 1024, 1);
  k_rowinv<<<4096, TPB, 0, stream>>>(xaw, inv);
  k_gemm128<<<dim3(16, 32), TPB, 0, stream>>>(xaw, inv, wkvn, Wkv, bkv, K, V, 2048, 2);
  k_rope<<<8192, TPB, 0, stream>>>(Q, 1023, cosb, sinb);
  k_rope<<<8192, TPB, 0, stream>>>(K, 1023, cosb, sinb);
  float* fout = xw;  // reuse
  k_proj<<<4096, TPB, 0, stream>>>(Q, K, V, qph, kphT, Wlq, blq, Wlk, blk, Wlv, blv, wln, 1024, nullptr);
  k_attn_t<8><<<512, TPB, 0, stream>>>(qph, kphT, V, Q, prev, fout, diffp, nullptr, 8, 16, 0);
  k_proj<<<4096, TPB, 0, stream>>>(Q, K, V, qph, kphT, Wlq, blq, Wlk, blk, Wlv, blv, wln, 1024, nullptr);
  k_attn_t<8><<<512, TPB, 0, stream>>>(qph, kphT, V, Q, prev, fout, diffp, nullptr, 8, 16, 1);
  k_finalize<<<1, 64, 0, stream>>>(diffp, flags, 1, 512, 4194304.0f);
  k_proj<<<4096, TPB, 0, stream>>>(Q, K, V, qph, kphT, Wlq, blq, Wlk, blk, Wlv, blv, wln, 1024, flags);
  k_attn_t<8><<<512, TPB, 0, stream>>>(qph, kphT, V, Q, prev, fout, diffp, flags, 8, 16, 2);

  k_gemm128<<<dim3(8, 32), TPB, 0, stream>>>(fout, nullptr, nullptr, Wo, bo, (float*)d_out, nullptr, 1024, 0);
}

// Round 3
// 2597.816 us; speedup vs baseline: 2.9442x; 2.9442x over previous
//
#include <hip/hip_runtime.h>
#include <math.h>

#define TPB 256

static __device__ __forceinline__ float4 mk4(float a, float b, float c, float d) {
  float4 r; r.x = a; r.y = b; r.z = c; r.w = d; return r;
}

// ---------------------------------------------------------------------------
// RoPE cos/sin tables, replicating JAX f32 arithmetic exactly. (unchanged)
// ---------------------------------------------------------------------------
__global__ __launch_bounds__(TPB) void k_tables(float* __restrict__ cosb,
                                                float* __restrict__ sinb) {
  int gid = blockIdx.x * TPB + threadIdx.x;
  if (gid >= 1024 * 32) return;
  int t = gid >> 5, j = gid & 31;
  const double Ld = 1.3222192947339193;  // python math.log10(21.0)
  float Lf = (float)Ld;
  float mlog;
  if (j == 31) {
    mlog = Lf;
  } else {
    float stepf = (float)((double)j / 31.0);
    mlog = (float)((double)Lf * (double)stepf);
  }
  float p = (float)pow(10.0, (double)mlog);
  float mel = p - 1.0f;
  float t2 = (200.0f * mel) / 1000.0f;
  float freq = 163.63636363636363f * t2;
  float ang = (float)t * freq;
  double a = (double)ang;
  cosb[gid] = (float)cos(a);
  sinb[gid] = (float)sin(a);
}

// ---------------------------------------------------------------------------
// Per-row 1/rms over D=1024 (unchanged)
// ---------------------------------------------------------------------------
__global__ __launch_bounds__(TPB) void k_rowinv(const float* __restrict__ X,
                                                float* __restrict__ inv) {
  __shared__ float red[4];
  int row = blockIdx.x;
  int tid = threadIdx.x;
  float4 v = *(const float4*)(X + (size_t)row * 1024 + tid * 4);
  float ss = v.x * v.x + v.y * v.y + v.z * v.z + v.w * v.w;
#pragma unroll
  for (int m = 1; m < 64; m <<= 1) ss += __shfl_xor(ss, m);
  if ((tid & 63) == 0) red[tid >> 6] = ss;
  __syncthreads();
  if (tid == 0) {
    float s = ((red[0] + red[1]) + (red[2] + red[3]));
    float mm = s * (1.0f / 1024.0f) + 1.1920928955078125e-7f;
    inv[row] = (float)(1.0 / sqrt((double)mm));
  }
}

// ---------------------------------------------------------------------------
// Tiled f32 GEMM, 128x128 block, BK=16, 8x8 per thread.
// NOTE: no min-occupancy clause in launch_bounds — round 2 showed that
// __launch_bounds__(TPB,4) capped VGPRs at 64 and spilled the 64-reg
// accumulator tile to scratch (1.6 GB fetch / 3.8 GB write per dispatch).
// ---------------------------------------------------------------------------
__global__ __launch_bounds__(TPB) void k_gemm128(
    const float* __restrict__ X, const float* __restrict__ inv,
    const float* __restrict__ wn, const float* __restrict__ W,
    const float* __restrict__ bias, float* __restrict__ o0,
    float* __restrict__ o1, int N, int mode) {
  __shared__ float As[16][132];
  __shared__ float Bs[16][132];
  int tid = threadIdx.x;
  int bx = blockIdx.x, by = blockIdx.y;
  int tx = tid & 15, ty = tid >> 4;
  float c[8][8];
#pragma unroll
  for (int i = 0; i < 8; ++i)
#pragma unroll
    for (int j = 0; j < 8; ++j) c[i][j] = 0.0f;

  int arow = tid >> 1;               // 0..127
  float sA = 1.0f;
  if (inv) sA = inv[by * 128 + arow];
  const float* Xrow = X + (size_t)(by * 128 + arow) * 1024;

  for (int k0 = 0; k0 < 1024; k0 += 16) {
    // stage A (transposed, scaled): 2 float4 per thread
#pragma unroll
    for (int u = 0; u < 2; ++u) {
      int kq = ((tid & 1) * 2 + u) * 4;
      float4 a4 = *(const float4*)(Xrow + k0 + kq);
      if (wn) {
        float4 w4 = *(const float4*)(wn + k0 + kq);
        a4.x *= w4.x; a4.y *= w4.y; a4.z *= w4.z; a4.w *= w4.w;
      }
      a4.x *= sA; a4.y *= sA; a4.z *= sA; a4.w *= sA;
      As[kq + 0][arow] = a4.x;
      As[kq + 1][arow] = a4.y;
      As[kq + 2][arow] = a4.z;
      As[kq + 3][arow] = a4.w;
    }
    // stage B: 2 float4 per thread
#pragma unroll
    for (int u = 0; u < 2; ++u) {
      int kr = tid >> 4;
      int c4 = ((tid & 15) * 2 + u) * 4;
      *(float4*)&Bs[kr][c4] =
          *(const float4*)(W + (size_t)(k0 + kr) * N + bx * 128 + c4);
    }
    __syncthreads();
#pragma unroll
    for (int kk = 0; kk < 16; ++kk) {
      float4 a0 = *(const float4*)&As[kk][ty * 4];
      float4 a1 = *(const float4*)&As[kk][64 + ty * 4];
      float4 b0 = *(const float4*)&Bs[kk][tx * 4];
      float4 b1 = *(const float4*)&Bs[kk][64 + tx * 4];
      float av[8] = {a0.x, a0.y, a0.z, a0.w, a1.x, a1.y, a1.z, a1.w};
      float bv[8] = {b0.x, b0.y, b0.z, b0.w, b1.x, b1.y, b1.z, b1.w};
#pragma unroll
      for (int i = 0; i < 8; ++i)
#pragma unroll
        for (int j = 0; j < 8; ++j) c[i][j] += av[i] * bv[j];
    }
    __syncthreads();
  }

  // writeback
#pragma unroll
  for (int jh = 0; jh < 2; ++jh) {
    int colbase = bx * 128 + jh * 64 + tx * 4;
    float4 bb = {0.f, 0.f, 0.f, 0.f};
    if (bias) bb = *(const float4*)(bias + colbase);
#pragma unroll
    for (int ih = 0; ih < 2; ++ih) {
#pragma unroll
      for (int i2 = 0; i2 < 4; ++i2) {
        int row = by * 128 + ih * 64 + ty * 4 + i2;
        int ci = ih * 4 + i2;
        float4 o;
        o.x = c[ci][jh * 4 + 0] + bb.x;
        o.y = c[ci][jh * 4 + 1] + bb.y;
        o.z = c[ci][jh * 4 + 2] + bb.z;
        o.w = c[ci][jh * 4 + 3] + bb.w;
        if (mode == 0) {
          *(float4*)(o0 + (size_t)row * N + colbase) = o;
        } else {
          int b = row >> 10, t = row & 1023;
          float* dst = o0;
          int cc = colbase;
          if (mode == 2 && colbase >= 1024) { dst = o1; cc = colbase - 1024; }
          int ch = cc >> 6, d = cc & 63;
          *(float4*)(dst + ((size_t)((b * 16 + ch) * 1024 + t)) * 64 + d) = o;
        }
      }
    }
  }
}

// ---------------------------------------------------------------------------
// In-place RoPE (unchanged)
// ---------------------------------------------------------------------------
__global__ __launch_bounds__(TPB) void k_rope(float* __restrict__ A, int mask,
                                              const float* __restrict__ cosb,
                                              const float* __restrict__ sinb) {
  int gid = blockIdx.x * TPB + threadIdx.x;
  int j = gid & 31;
  int row = gid >> 5;
  int t = row & 1023;
  int aidx = ((t & mask) << 5) + j;
  float cc = cosb[aidx], sn = sinb[aidx];
  size_t base = (size_t)row * 64;
  float x1 = A[base + 2 * j], x2 = A[base + 2 * j + 1];
  A[base + 2 * j] = x1 * cc - x2 * sn;
  A[base + 2 * j + 1] = x1 * sn + x2 * cc;
}

// ---------------------------------------------------------------------------
// Slide gather (unchanged)
// ---------------------------------------------------------------------------
__global__ __launch_bounds__(TPB) void k_gather(
    const float* __restrict__ K, const float* __restrict__ V,
    float* __restrict__ kc, float* __restrict__ vc,
    const float* __restrict__ cosb, const float* __restrict__ sinb) {
  int gid = blockIdx.x * TPB + threadIdx.x;
  int j = gid & 31;
  int tl = (gid >> 5) & 63;
  int win = (gid >> 11) & 15;
  int h = (gid >> 15) & 15;
  int b = gid >> 19;
  int sw = win * 64 - 4;
  if (win == 0) sw = 0;
  size_t bh = (size_t)(b * 16 + h) * 1024;
  size_t src = (bh + sw + tl) * 64;
  size_t dst = (bh + win * 64 + tl) * 64;
  int aidx = (tl << 5) + j;
  float cc = cosb[aidx], sn = sinb[aidx];
  float k1 = K[src + 2 * j], k2 = K[src + 2 * j + 1];
  kc[dst + 2 * j] = k1 * cc - k2 * sn;
  kc[dst + 2 * j + 1] = k1 * sn + k2 * cc;
  vc[dst + 2 * j] = V[src + 2 * j];
  vc[dst + 2 * j + 1] = V[src + 2 * j + 1];
}

// ---------------------------------------------------------------------------
// Projections (unchanged from round 2): qph normed, kc raw kp, kphT normed
// transposed, vc = vp.  Weights staged in LDS.
// ---------------------------------------------------------------------------
__global__ __launch_bounds__(TPB) void k_proj(
    const float* __restrict__ curq, float* __restrict__ kc,
    float* __restrict__ vc, float* __restrict__ qph, float* __restrict__ kphT,
    const float* __restrict__ Wlq, const float* __restrict__ blq,
    const float* __restrict__ Wlk, const float* __restrict__ blk,
    const float* __restrict__ Wlv, const float* __restrict__ blv,
    const float* __restrict__ wln, int CQ, const int* __restrict__ flags) {
  int RT = CQ >> 4;
  int bid = blockIdx.x;
  int rt = bid % RT;
  int rest = bid / RT;
  int h = rest & 15; rest >>= 4;
  int b = rest & 3;
  int win = rest >> 2;
  if (flags && flags[win]) return;
  __shared__ float qs[16][68], ksm[16][68], vsm[16][68];
  __shared__ float Wqs[4096], Wks[4096], Wvs[4096];
  int tid = threadIdx.x;
#pragma unroll
  for (int i = 0; i < 4; ++i) {
    int f4 = (i * 256 + tid) * 4;
    *(float4*)&Wqs[f4] = *(const float4*)(Wlq + f4);
    *(float4*)&Wks[f4] = *(const float4*)(Wlk + f4);
    *(float4*)&Wvs[f4] = *(const float4*)(Wlv + f4);
  }
  int lr = tid >> 4, c4 = (tid & 15) * 4;
  int bh = b * 16 + h;
  size_t rowbase = (size_t)bh * 1024 + (size_t)win * CQ + rt * 16;
  size_t g = (rowbase + lr) * 64 + c4;
  *(float4*)&qs[lr][c4] = *(const float4*)(curq + g);
  *(float4*)&ksm[lr][c4] = *(const float4*)(kc + g);
  *(float4*)&vsm[lr][c4] = *(const float4*)(vc + g);
  __syncthreads();
  int r = tid >> 4, cg = tid & 15;
  int tglob = win * CQ + rt * 16 + r;
  const float eps = 1.1920928955078125e-7f;
  float4 wl4 = *(const float4*)(wln + cg * 4);
  size_t orow = (rowbase + r) * 64 + cg * 4;
  float4 acc;
  float ssum, rms;
  // ---- Q
  acc = *(const float4*)(blq + cg * 4);
#pragma unroll 8
  for (int k = 0; k < 64; ++k) {
    float xv = qs[r][k];
    float4 w4 = *(const float4*)&Wqs[k * 64 + cg * 4];
    acc.x += xv * w4.x; acc.y += xv * w4.y;
    acc.z += xv * w4.z; acc.w += xv * w4.w;
  }
  ssum = acc.x * acc.x + acc.y * acc.y + acc.z * acc.z + acc.w * acc.w;
#pragma unroll
  for (int m = 1; m < 16; m <<= 1) ssum += __shfl_xor(ssum, m);
  rms = (float)(1.0 / sqrt((double)(ssum * 0.015625f + eps)));
  {
    float4 o;
    o.x = acc.x * rms * wl4.x; o.y = acc.y * rms * wl4.y;
    o.z = acc.z * rms * wl4.z; o.w = acc.w * rms * wl4.w;
    *(float4*)(qph + orow) = o;
  }
  // ---- K
  acc = *(const float4*)(blk + cg * 4);
#pragma unroll 8
  for (int k = 0; k < 64; ++k) {
    float xv = ksm[r][k];
    float4 w4 = *(const float4*)&Wks[k * 64 + cg * 4];
    acc.x += xv * w4.x; acc.y += xv * w4.y;
    acc.z += xv * w4.z; acc.w += xv * w4.w;
  }
  *(float4*)(kc + orow) = acc;  // raw kp -> next kc
  ssum = acc.x * acc.x + acc.y * acc.y + acc.z * acc.z + acc.w * acc.w;
#pragma unroll
  for (int m = 1; m < 16; m <<= 1) ssum += __shfl_xor(ssum, m);
  rms = (float)(1.0 / sqrt((double)(ssum * 0.015625f + eps)));
  {
    float no0 = acc.x * rms * wl4.x;
    float no1 = acc.y * rms * wl4.y;
    float no2 = acc.z * rms * wl4.z;
    float no3 = acc.w * rms * wl4.w;
    size_t tb = (size_t)bh * 64 + cg * 4;
    kphT[(tb + 0) * 1024 + tglob] = no0;
    kphT[(tb + 1) * 1024 + tglob] = no1;
    kphT[(tb + 2) * 1024 + tglob] = no2;
    kphT[(tb + 3) * 1024 + tglob] = no3;
  }
  // ---- V
  acc = *(const float4*)(blv + cg * 4);
#pragma unroll 8
  for (int k = 0; k < 64; ++k) {
    float xv = vsm[r][k];
    float4 w4 = *(const float4*)&Wvs[k * 64 + cg * 4];
    acc.x += xv * w4.x; acc.y += xv * w4.y;
    acc.z += xv * w4.z; acc.w += xv * w4.w;
  }
  *(float4*)(vc + orow) = acc;
}

// ---------------------------------------------------------------------------
// Attention, outer-product register-blocked flash (unchanged from round 2).
// ---------------------------------------------------------------------------
template <int FRAG>
__global__ __launch_bounds__(TPB, 2) void k_attn_t(
    const float* __restrict__ qph, const float* __restrict__ kphT,
    const float* __restrict__ vbuf, float* __restrict__ curq,
    float* __restrict__ prevb, float* __restrict__ outb,
    float* __restrict__ diffp, const int* __restrict__ flags, int NQT,
    int nt, int mode) {
  constexpr int QT = FRAG * 16;
  int bid = blockIdx.x;
  int qt = bid % NQT;
  int bh = bid / NQT;
  int h = bh & 15, b = bh >> 4;
  if (mode == 2 && flags[(nt == 1) ? qt : 0]) return;
  __shared__ float qTs[64][QT];
  __shared__ float kps[64 * QT];  // kT [d][k<64] then pT [k][q]
  __shared__ float vss[64 * 64];
  int tid = threadIdx.x;
  int tx = tid & 15, ty = tid >> 4;
  size_t bh1024 = (size_t)bh * 1024;
  size_t bh64 = (size_t)bh * 64;
  int q0 = qt * QT;
#pragma unroll
  for (int i = 0; i < FRAG; ++i) {
    int f4id = i * 256 + tid;
    int row = f4id >> 4;
    int c4 = (f4id & 15) * 4;
    float4 v = *(const float4*)(qph + (bh1024 + q0 + row) * 64 + c4);
    qTs[c4 + 0][row] = v.x;
    qTs[c4 + 1][row] = v.y;
    qTs[c4 + 2][row] = v.z;
    qTs[c4 + 3][row] = v.w;
  }
  float m[FRAG], l[FRAG], acc[FRAG][4];
#pragma unroll
  for (int i = 0; i < FRAG; ++i) {
    m[i] = -INFINITY; l[i] = 0.0f;
    acc[i][0] = acc[i][1] = acc[i][2] = acc[i][3] = 0.0f;
  }
  int kstart = (nt == 1) ? q0 : 0;
  const float SCL = 0.18033688011112042f;  // log2(e)/8

  for (int kt = 0; kt < nt; ++kt) {
    int k0 = kstart + kt * 64;
#pragma unroll
    for (int i = 0; i < 4; ++i) {
      int f4id = i * 256 + tid;
      int rr = f4id >> 4;
      int c4 = (f4id & 15) * 4;
      *(float4*)&kps[rr * QT + c4] =
          *(const float4*)(kphT + (bh64 + rr) * 1024 + k0 + c4);
      *(float4*)&vss[rr * 64 + c4] =
          *(const float4*)(vbuf + (bh1024 + k0 + rr) * 64 + c4);
    }
    __syncthreads();
    float s[FRAG][4];
#pragma unroll
    for (int i = 0; i < FRAG; ++i)
      s[i][0] = s[i][1] = s[i][2] = s[i][3] = 0.0f;
#pragma unroll 4
    for (int d = 0; d < 64; ++d) {
      float4 kv = *(const float4*)&kps[d * QT + tx * 4];
      float4 qa0 = *(const float4*)&qTs[d][ty * FRAG];
      float qv[FRAG];
      qv[0] = qa0.x; qv[1] = qa0.y; qv[2] = qa0.z; qv[3] = qa0.w;
      if (FRAG == 8) {
        float4 qa1 = *(const float4*)&qTs[d][ty * FRAG + 4];
        qv[4] = qa1.x; qv[5] = qa1.y; qv[6] = qa1.z; qv[7] = qa1.w;
      }
#pragma unroll
      for (int i = 0; i < FRAG; ++i) {
        s[i][0] += qv[i] * kv.x;
        s[i][1] += qv[i] * kv.y;
        s[i][2] += qv[i] * kv.z;
        s[i][3] += qv[i] * kv.w;
      }
    }
#pragma unroll
    for (int i = 0; i < FRAG; ++i) {
      s[i][0] *= SCL; s[i][1] *= SCL; s[i][2] *= SCL; s[i][3] *= SCL;
      float r0 = fmaxf(fmaxf(s[i][0], s[i][1]), fmaxf(s[i][2], s[i][3]));
#pragma unroll
      for (int mm = 1; mm < 16; mm <<= 1) r0 = fmaxf(r0, __shfl_xor(r0, mm));
      float mnew = fmaxf(m[i], r0);
      float sc = exp2f(m[i] - mnew);
      float rs = 0.0f;
#pragma unroll
      for (int j = 0; j < 4; ++j) {
        float pv = exp2f(s[i][j] - mnew);
        s[i][j] = pv;
        rs += pv;
      }
#pragma unroll
      for (int mm = 1; mm < 16; mm <<= 1) rs += __shfl_xor(rs, mm);
      l[i] = l[i] * sc + rs;
      m[i] = mnew;
      acc[i][0] *= sc; acc[i][1] *= sc; acc[i][2] *= sc; acc[i][3] *= sc;
    }
    __syncthreads();  // all S reads of kps done
#pragma unroll
    for (int jj = 0; jj < 4; ++jj) {
      *(float4*)&kps[(tx * 4 + jj) * QT + ty * FRAG] =
          mk4(s[0][jj], s[1][jj], s[2][jj], s[3][jj]);
      if (FRAG == 8)
        *(float4*)&kps[(tx * 4 + jj) * QT + ty * FRAG + 4] =
            mk4(s[4][jj], s[5][jj], s[6][jj], s[7][jj]);
    }
    __syncthreads();
#pragma unroll 4
    for (int k = 0; k < 64; ++k) {
      float4 vv = *(const float4*)&vss[k * 64 + tx * 4];
      float4 pa0 = *(const float4*)&kps[k * QT + ty * FRAG];
      float pv[FRAG];
      pv[0] = pa0.x; pv[1] = pa0.y; pv[2] = pa0.z; pv[3] = pa0.w;
      if (FRAG == 8) {
        float4 pa1 = *(const float4*)&kps[k * QT + ty * FRAG + 4];
        pv[4] = pa1.x; pv[5] = pa1.y; pv[6] = pa1.z; pv[7] = pa1.w;
      }
#pragma unroll
      for (int i = 0; i < FRAG; ++i) {
        acc[i][0] += pv[i] * vv.x;
        acc[i][1] += pv[i] * vv.y;
        acc[i][2] += pv[i] * vv.z;
        acc[i][3] += pv[i] * vv.w;
      }
    }
    __syncthreads();
  }
  float ds = 0.0f;
#pragma unroll
  for (int i = 0; i < FRAG; ++i) {
    int t = q0 + ty * FRAG + i;
    float4 att;
    att.x = acc[i][0] / l[i];
    att.y = acc[i][1] / l[i];
    att.z = acc[i][2] / l[i];
    att.w = acc[i][3] / l[i];
    size_t base = (bh1024 + t) * 64 + tx * 4;
    size_t obase = ((size_t)b * 1024 + t) * 1024 + h * 64 + tx * 4;
    if (mode == 0) {
      *(float4*)(prevb + base) = att;
      float4 cq = *(const float4*)(curq + base);
      cq.x += att.x; cq.y += att.y; cq.z += att.z; cq.w += att.w;
      *(float4*)(curq + base) = cq;
    } else if (mode == 1) {
      float4 pv = *(const float4*)(prevb + base);
      ds += fabsf(att.x - pv.x) + fabsf(att.y - pv.y) +
            fabsf(att.z - pv.z) + fabsf(att.w - pv.w);
      float4 cq = *(const float4*)(curq + base);
      cq.x += att.x; cq.y += att.y; cq.z += att.z; cq.w += att.w;
      *(float4*)(curq + base) = cq;
      *(float4*)(outb + obase) = att;
    } else {
      *(float4*)(outb + obase) = att;
    }
  }
  if (mode == 1) {
    float* red = vss;  // vss dead
    red[tid] = ds;
    __syncthreads();
    for (int s2 = 128; s2 > 0; s2 >>= 1) {
      if (tid < s2) red[tid] += red[tid + s2];
      __syncthreads();
    }
    if (tid == 0) diffp[bid] = red[0];
  }
}

// Deterministic diff finalize.  flags[w] = mean over window < 0.5
__global__ __launch_bounds__(64) void k_finalize(const float* __restrict__ diffp,
                                                 int* __restrict__ flags,
                                                 int nwin, int nper,
                                                 float count) {
  int w = threadIdx.x;
  if (w < nwin) {
    float s = 0.0f;
    for (int i = 0; i < nper; ++i) s += diffp[w + i * nwin];
    flags[w] = (s / count < 0.5f) ? 1 : 0;
  }
}

// ---------------------------------------------------------------------------
extern "C" void kernel_launch(void* const* d_in, const int* in_sizes, int n_in,
                              void* d_out, int out_size, void* d_ws,
                              size_t ws_size, hipStream_t stream) {
  const float* x = (const float*)d_in[0];
  const float* xa = (const float*)d_in[1];
  const float* wqn = (const float*)d_in[2];
  const float* Wq = (const float*)d_in[3];
  const float* bq = (const float*)d_in[4];
  const float* wkvn = (const float*)d_in[5];
  const float* Wkv = (const float*)d_in[6];
  const float* bkv = (const float*)d_in[7];
  const float* wln = (const float*)d_in[8];
  const float* Wlq = (const float*)d_in[9];
  const float* blq = (const float*)d_in[10];
  const float* Wlk = (const float*)d_in[11];
  const float* blk = (const float*)d_in[12];
  const float* Wlv = (const float*)d_in[13];
  const float* blv = (const float*)d_in[14];
  const float* Wo = (const float*)d_in[15];
  const float* bo = (const float*)d_in[16];

  float* ws = (float*)d_ws;
  const size_t SLOT = (size_t)4 * 16 * 1024 * 64;  // 16 MiB
  float* xw = ws;
  float* xaw = ws + SLOT;
  float* Q = ws + 2 * SLOT;  // curq
  float* K = ws + 3 * SLOT;
  float* V = ws + 4 * SLOT;
  float* kc = ws + 5 * SLOT;
  float* vc = ws + 6 * SLOT;
  float* prev = ws + 7 * SLOT;
  float* qph = ws + 8 * SLOT;
  float* kphT = ws + 9 * SLOT;
  float* misc = ws + 10 * SLOT;
  float* inv = misc;
  float* cosb = misc + 8192;
  float* sinb = cosb + 32768;
  float* diffp = sinb + 32768;
  int* flags = (int*)(diffp + 4096);

  k_tables<<<128, TPB, 0, stream>>>(cosb, sinb);

  for (int sl = 0; sl < 2; ++sl) {
    const float* Xin = sl ? xa : x;
    float* Xout = sl ? xaw : xw;
    k_rowinv<<<4096, TPB, 0, stream>>>(Xin, inv);
    k_gemm128<<<dim3(8, 32), TPB, 0, stream>>>(Xin, inv, wqn, Wq, bq, Q, nullptr, 1024, 1);
    k_gemm128<<<dim3(16, 32), TPB, 0, stream>>>(Xin, inv, wkvn, Wkv, bkv, K, V, 2048, 2);
    k_rope<<<8192, TPB, 0, stream>>>(Q, 63, cosb, sinb);
    k_gather<<<8192, TPB, 0, stream>>>(K, V, kc, vc, cosb, sinb);
    // it0
    k_proj<<<4096, TPB, 0, stream>>>(Q, kc, vc, qph, kphT, Wlq, blq, Wlk, blk, Wlv, blv, wln, 64, nullptr);
    k_attn_t<4><<<1024, TPB, 0, stream>>>(qph, kphT, vc, Q, prev, Xout, diffp, nullptr, 16, 1, 0);
    // it1
    k_proj<<<4096, TPB, 0, stream>>>(Q, kc, vc, qph, kphT, Wlq, blq, Wlk, blk, Wlv, blv, wln, 64, nullptr);
    k_attn_t<4><<<1024, TPB, 0, stream>>>(qph, kphT, vc, Q, prev, Xout, diffp, nullptr, 16, 1, 1);
    k_finalize<<<1, 64, 0, stream>>>(diffp, flags, 16, 64, 262144.0f);
    // it2
    k_proj<<<4096, TPB, 0, stream>>>(Q, kc, vc, qph, kphT, Wlq, blq, Wlk, blk, Wlv, blv, wln, 64, flags);
    k_attn_t<4><<<1024, TPB, 0, stream>>>(qph, kphT, vc, Q, prev, Xout, diffp, flags, 16, 1, 2);
  }

  // final focus: cq = ck = 1024
  k_rowinv<<<4096, TPB, 0, stream>>>(xw, inv);
  k_gemm128<<<dim3(8, 32), TPB, 0, stream>>>(xw, inv, wqn, Wq, bq, Q, nullptr, 1024, 1);
  k_rowinv<<<4096, TPB, 0, stream>>>(xaw, inv);
  k_gemm128<<<dim3(16, 32), TPB, 0, stream>>>(xaw, inv, wkvn, Wkv, bkv, K, V, 2048, 2);
  k_rope<<<8192, TPB, 0, stream>>>(Q, 1023, cosb, sinb);
  k_rope<<<8192, TPB, 0, stream>>>(K, 1023, cosb, sinb);
  float* fout = xw;  // reuse
  k_proj<<<4096, TPB, 0, stream>>>(Q, K, V, qph, kphT, Wlq, blq, Wlk, blk, Wlv, blv, wln, 1024, nullptr);
  k_attn_t<8><<<512, TPB, 0, stream>>>(qph, kphT, V, Q, prev, fout, diffp, nullptr, 8, 16, 0);
  k_proj<<<4096, TPB, 0, stream>>>(Q, K, V, qph, kphT, Wlq, blq, Wlk, blk, Wlv, blv, wln, 1024, nullptr);
  k_attn_t<8><<<512, TPB, 0, stream>>>(qph, kphT, V, Q, prev, fout, diffp, nullptr, 8, 16, 1);
  k_finalize<<<1, 64, 0, stream>>>(diffp, flags, 1, 512, 4194304.0f);
  k_proj<<<4096, TPB, 0, stream>>>(Q, K, V, qph, kphT, Wlq, blq, Wlk, blk, Wlv, blv, wln, 1024, flags);
  k_attn_t<8><<<512, TPB, 0, stream>>>(qph, kphT, V, Q, prev, fout, diffp, flags, 8, 16, 2);

  k_gemm128<<<dim3(8, 32), TPB, 0, stream>>>(fout, nullptr, nullptr, Wo, bo, (float*)d_out, nullptr, 1024, 0);
}